// Round 1
// baseline (192.880 us; speedup 1.0000x reference)
//
#include <hip/hip_runtime.h>
#include <hip/hip_bf16.h>

#define PP     512
#define KK     64
#define BB     32
#define LLEN   2048
#define SROWS  74           // 64 output positions + 2*5 conv halo

typedef __attribute__((ext_vector_type(8)))  short short8;
typedef __attribute__((ext_vector_type(16))) float float16;

__device__ inline unsigned int pack_bf2(float lo, float hi) {
    __hip_bfloat162 h = __float22bfloat162_rn(make_float2(lo, hi));
    unsigned int u;
    __builtin_memcpy(&u, &h, 4);
    return u;   // low 16 = lo, high 16 = hi
}
__device__ inline float bf_lo(unsigned int v) { return __uint_as_float(v << 16); }
__device__ inline float bf_hi(unsigned int v) { return __uint_as_float(v & 0xffff0000u); }

// ---------------------------------------------------------------------------
// K1: unified B-operand fragments, 128 cols: n<64 -> l_hat[n], n>=64 -> f2w[n-64].
// Bu4[f*128 + n] = 8 bf16 of src[n][8f..8f+7] (f = 0..63).  (unchanged)
// ---------------------------------------------------------------------------
__global__ void k1_prep(const float* __restrict__ C, const float* __restrict__ f2w,
                        ushort* __restrict__ Bu) {
    const int n = blockIdx.x;            // 0..127
    const float* src = (n < 64) ? (C + n * PP) : (f2w + (n - 64) * PP);
    const int t = threadIdx.x;
    float v0 = src[t];
    float v1 = src[t + 256];
    __shared__ float red[256];
    red[t] = v0 * v0 + v1 * v1;
    __syncthreads();
    for (int s = 128; s > 0; s >>= 1) {
        if (t < s) red[t] += red[t + s];
        __syncthreads();
    }
    const float inv = (n < 64) ? rsqrtf(red[0]) : 1.f;
    Bu[(((t >> 3)       * 128 + n) << 3) + (t & 7)] = (ushort)(pack_bf2(v0 * inv, 0.f) & 0xffffu);
    Bu[((((t + 256) >> 3)) * 128 + n) * 8 + (t & 7)] = (ushort)(pack_bf2(v1 * inv, 0.f) & 0xffffu);
}

// ---------------------------------------------------------------------------
// K2 fused: per (b, 64-pos chunk): stage 74 token rows (halo included) as
// xor-swizzled bf16 in LDS, MFMA cos (74 rows x 64 labels) + E2 (64 rows x 64),
// then IN-BLOCK: conv(11) -> relu -> max_k -> chunk softmax partial -> pooled
// E2 partial. G (bf16 pairs) and E2 (f32) alias the dead A-tile LDS.
// Output: pool[blk][0..63]=partial, [64]=chunk max, [65]=chunk expsum.
// ---------------------------------------------------------------------------
__launch_bounds__(256, 2)
__global__ void k2_fused(const int* __restrict__ x, const float* __restrict__ V,
                         const uint4* __restrict__ Bu4,
                         const float* __restrict__ f1w, const float* __restrict__ f1b,
                         float* __restrict__ pool) {
    __shared__ uint4 sA[SROWS * 64];     // 75776 B; G32 + E2s alias after MFMA
    __shared__ int   stok[SROWS];
    __shared__ float rnorm[SROWS];
    __shared__ float smv[64];
    __shared__ float sp[64];
    __shared__ float sscal[2];
    __shared__ float sred[8][64];

    const int tid  = threadIdx.x;
    const int lane = tid & 63;
    const int wv   = tid >> 6;
    const int l31  = lane & 31;
    const int b    = blockIdx.x >> 5;
    const int l0   = (blockIdx.x & 31) * 64;

    if (tid < SROWS) {
        int gl = l0 - 5 + tid;
        gl = min(max(gl, 0), LLEN - 1);    // clamp; invalid rows zeroed at G-write
        stok[tid] = x[b * LLEN + gl];
    }
    __syncthreads();

    const int q = tid & 3;
    // ---- staging pass 1: rows 0..63 (each quad stages one 2KB row) ----
    {
        const int r    = tid >> 2;
        const float* src = V + (size_t)stok[r] * PP + q * 4;
        const int swzr = r & 7;
        float nrm = 0.f;
        float4 pa[16];
#pragma unroll
        for (int g = 0; g < 16; ++g) pa[g] = ((const float4*)src)[g * 4];
        float4 pb[16];
#pragma unroll
        for (int g = 0; g < 16; ++g) pb[g] = ((const float4*)src)[(g + 16) * 4];
#pragma unroll
        for (int g = 0; g < 16; ++g) {
            const float4 a = pa[g];
            nrm = fmaf(a.x, a.x, fmaf(a.y, a.y, fmaf(a.z, a.z, fmaf(a.w, a.w, nrm))));
            uint2 w2; w2.x = pack_bf2(a.x, a.y); w2.y = pack_bf2(a.z, a.w);
            const int f = g * 2 + (q >> 1);
            ((uint2*)&sA[r * 64 + (f ^ swzr)])[q & 1] = w2;
        }
#pragma unroll
        for (int g = 0; g < 16; ++g) {
            const float4 a = pb[g];
            nrm = fmaf(a.x, a.x, fmaf(a.y, a.y, fmaf(a.z, a.z, fmaf(a.w, a.w, nrm))));
            uint2 w2; w2.x = pack_bf2(a.x, a.y); w2.y = pack_bf2(a.z, a.w);
            const int f = (g + 16) * 2 + (q >> 1);
            ((uint2*)&sA[r * 64 + (f ^ swzr)])[q & 1] = w2;
        }
        nrm += __shfl_xor(nrm, 1, 64);
        nrm += __shfl_xor(nrm, 2, 64);
        if (q == 0) rnorm[r] = rsqrtf(nrm);
    }
    // ---- staging pass 2: halo rows 64..73 (threads 0..39, quads 0..9) ----
    if (tid < 40) {
        const int r    = 64 + (tid >> 2);
        const float* src = V + (size_t)stok[r] * PP + q * 4;
        const int swzr = r & 7;
        float nrm = 0.f;
        float4 pa[16];
#pragma unroll
        for (int g = 0; g < 16; ++g) pa[g] = ((const float4*)src)[g * 4];
        float4 pb[16];
#pragma unroll
        for (int g = 0; g < 16; ++g) pb[g] = ((const float4*)src)[(g + 16) * 4];
#pragma unroll
        for (int g = 0; g < 16; ++g) {
            const float4 a = pa[g];
            nrm = fmaf(a.x, a.x, fmaf(a.y, a.y, fmaf(a.z, a.z, fmaf(a.w, a.w, nrm))));
            uint2 w2; w2.x = pack_bf2(a.x, a.y); w2.y = pack_bf2(a.z, a.w);
            const int f = g * 2 + (q >> 1);
            ((uint2*)&sA[r * 64 + (f ^ swzr)])[q & 1] = w2;
        }
#pragma unroll
        for (int g = 0; g < 16; ++g) {
            const float4 a = pb[g];
            nrm = fmaf(a.x, a.x, fmaf(a.y, a.y, fmaf(a.z, a.z, fmaf(a.w, a.w, nrm))));
            uint2 w2; w2.x = pack_bf2(a.x, a.y); w2.y = pack_bf2(a.z, a.w);
            const int f = (g + 16) * 2 + (q >> 1);
            ((uint2*)&sA[r * 64 + (f ^ swzr)])[q & 1] = w2;
        }
        nrm += __shfl_xor(nrm, 1, 64);
        nrm += __shfl_xor(nrm, 2, 64);
        if (q == 0) rnorm[r] = rsqrtf(nrm);
    }
    __syncthreads();

    // ---- MFMA: 5 wave-tiles of 32 rows x 64 cols (cos: staged rows
    //      {0-31, 32-63, 42-73}; E2: staged rows {5-36, 37-68}) ----
    float16 c0, c1, d0, d1;
#pragma unroll
    for (int i = 0; i < 16; ++i) { c0[i] = 0.f; c1[i] = 0.f; d0[i] = 0.f; d1[i] = 0.f; }

    auto tile = [&](int rowBase, int nh, float16& A0, float16& A1) {
        const int cc    = lane >> 5;
        const int row   = rowBase + l31;
        const int abase = row * 64;
        const int aswz  = row & 7;
#pragma unroll 8
        for (int ks = 0; ks < 32; ++ks) {
            const int ff = ks * 2 + cc;
            const uint4 av = sA[abase + (ff ^ aswz)];
            const uint4 b0 = Bu4[ff * 128 + nh + l31];
            const uint4 b1 = Bu4[ff * 128 + nh + 32 + l31];
            short8 a8, t0, t1;
            __builtin_memcpy(&a8, &av, 16);
            __builtin_memcpy(&t0, &b0, 16);
            __builtin_memcpy(&t1, &b1, 16);
            A0 = __builtin_amdgcn_mfma_f32_32x32x16_bf16(a8, t0, A0, 0, 0, 0);
            A1 = __builtin_amdgcn_mfma_f32_32x32x16_bf16(a8, t1, A1, 0, 0, 0);
        }
    };
    if      (wv == 0) { tile(0, 0, c0, c1); }
    else if (wv == 1) { tile(32, 0, c0, c1); }
    else if (wv == 2) { tile(42, 0, c0, c1); tile(37, 64, d0, d1); }
    else              { tile(5, 64, d0, d1); }
    __syncthreads();   // all A-tile reads done -> safe to alias sA

    // ---- scatter results into aliased LDS ----
    unsigned int* G32 = (unsigned int*)sA;             // [SROWS][32], pairs (j, j+32)
    float*        E2s = (float*)((char*)sA + 10240);   // [64][64] f32
    const int cc = lane >> 5;
    if (wv < 3) {                                       // cos waves
        const int rowBase = (wv == 0) ? 0 : (wv == 1) ? 32 : 42;
#pragma unroll
        for (int reg = 0; reg < 16; ++reg) {
            const int rr  = (reg & 3) + 8 * (reg >> 2) + 4 * cc;
            const int row = rowBase + rr;
            if (wv == 2 && row < 64) continue;          // overlap rows: wv1 owns them
            const int gl = l0 - 5 + row;
            unsigned int vpk = 0u;
            if (gl >= 0 && gl < LLEN) {
                const float rn = rnorm[row];
                vpk = pack_bf2(c0[reg] * rn, c1[reg] * rn);
            }
            G32[row * 32 + l31] = vpk;
        }
    }
    if (wv >= 2) {                                      // E2 waves
        const int rowBase = (wv == 2) ? 37 : 5;
#pragma unroll
        for (int reg = 0; reg < 16; ++reg) {
            const int rr = (reg & 3) + 8 * (reg >> 2) + 4 * cc;
            const int o  = rowBase - 5 + rr;            // 0..63
            E2s[o * 64 + l31]      = d0[reg];
            E2s[o * 64 + 32 + l31] = d1[reg];
        }
    }
    __syncthreads();

    // ---- conv(11) + relu + max over k ----
    float w[11];
#pragma unroll
    for (int t = 0; t < 11; ++t) w[t] = f1w[t];
    const int j = l31;
    const int h = tid >> 5;                              // 0..7
    const float bias0 = f1b[j], bias1 = f1b[j + 32];
#pragma unroll
    for (int i = 0; i < 8; ++i) {
        const int o = i * 8 + h;                         // output row 0..63
        float u0 = 0.f, u1 = 0.f;
#pragma unroll
        for (int tap = 0; tap < 11; ++tap) {
            const unsigned int v = G32[(o + tap) * 32 + j];
            u0 = fmaf(bf_lo(v), w[tap], u0);
            u1 = fmaf(bf_hi(v), w[tap], u1);
        }
        float m = fmaxf(fmaxf(u0 + bias0, 0.f), fmaxf(u1 + bias1, 0.f));
#pragma unroll
        for (int off = 16; off > 0; off >>= 1)
            m = fmaxf(m, __shfl_xor(m, off, 64));
        if (j == 0) smv[o] = m;
    }
    __syncthreads();

    // ---- chunk softmax partials ----
    if (tid < 64) {
        float v = smv[tid];
#pragma unroll
        for (int off = 32; off > 0; off >>= 1)
            v = fmaxf(v, __shfl_xor(v, off, 64));
        if (tid == 0) sscal[0] = v;
    }
    __syncthreads();
    const float mx = sscal[0];
    if (tid < 64) sp[tid] = __expf(smv[tid] - mx);
    __syncthreads();
    if (tid < 64) {
        float s = sp[tid];
#pragma unroll
        for (int off = 32; off > 0; off >>= 1)
            s += __shfl_xor(s, off, 64);
        if (tid == 0) sscal[1] = s;
    }

    // ---- weighted E2 pooling (f32) ----
    float a0 = 0.f, a1 = 0.f;
#pragma unroll
    for (int i = 0; i < 8; ++i) {
        const int o = i * 8 + h;
        const float wgt = sp[o];
        a0 = fmaf(wgt, E2s[o * 64 + j], a0);
        a1 = fmaf(wgt, E2s[o * 64 + 32 + j], a1);
    }
    sred[h][j]      = a0;
    sred[h][j + 32] = a1;
    __syncthreads();
    if (tid < 64) {
        float r = 0.f;
#pragma unroll
        for (int hh = 0; hh < 8; ++hh) r += sred[hh][tid];
        float* dst = pool + (size_t)blockIdx.x * 68;
        dst[tid] = r;
        if (tid == 0) { dst[64] = sscal[0]; dst[65] = sscal[1]; }
    }
}

// ---------------------------------------------------------------------------
// K6: combine 32 chunk-partials per b with online-softmax rescale + head bias.
// ---------------------------------------------------------------------------
__global__ void k6_final(const float* __restrict__ pool, const float* __restrict__ f2b,
                         float* __restrict__ out) {
    const int b = blockIdx.x;
    const int k = threadIdx.x;   // 64 threads
    float M = -1e30f;
#pragma unroll
    for (int c = 0; c < 32; ++c)
        M = fmaxf(M, pool[(size_t)(b * 32 + c) * 68 + 64]);
    float tot = 0.f, num = 0.f;
#pragma unroll
    for (int c = 0; c < 32; ++c) {
        const float* pc = pool + (size_t)(b * 32 + c) * 68;
        const float sc = __expf(pc[64] - M);
        tot = fmaf(sc, pc[65], tot);
        num = fmaf(sc, pc[k], num);
    }
    out[b * KK + k] = (num / tot) * (1.f / 2048.f) + f2b[k];
}

extern "C" void kernel_launch(void* const* d_in, const int* in_sizes, int n_in,
                              void* d_out, int out_size, void* d_ws, size_t ws_size,
                              hipStream_t stream) {
    const int*   x   = (const int*)d_in[0];
    const float* V   = (const float*)d_in[1];
    const float* C   = (const float*)d_in[2];
    const float* f1w = (const float*)d_in[3];
    const float* f1b = (const float*)d_in[4];
    const float* f2w = (const float*)d_in[5];
    const float* f2b = (const float*)d_in[6];
    float* out = (float*)d_out;

    float* ws = (float*)d_ws;
    ushort* Bu = (ushort*)ws;                 // 65536 ushort = 128 KB
    float* pool = ws + 32768;                 // 1024 * 68 floats

    k1_prep <<<128, 256, 0, stream>>>(C, f2w, Bu);
    k2_fused<<<BB * 32, 256, 0, stream>>>(x, V, (const uint4*)Bu, f1w, f1b, pool);
    k6_final<<<BB, 64, 0, stream>>>(pool, f2b, out);
}

// Round 2
// 170.018 us; speedup vs baseline: 1.1345x; 1.1345x over previous
//
#include <hip/hip_runtime.h>
#include <hip/hip_bf16.h>

#define PP     512
#define KK     64
#define BB     32
#define LLEN   2048
#define SROWS  74           // 64 output positions + 2*5 conv halo

typedef __attribute__((ext_vector_type(8)))  short short8;
typedef __attribute__((ext_vector_type(16))) float float16;

__device__ inline unsigned int pack_bf2(float lo, float hi) {
    __hip_bfloat162 h = __float22bfloat162_rn(make_float2(lo, hi));
    unsigned int u;
    __builtin_memcpy(&u, &h, 4);
    return u;   // low 16 = lo, high 16 = hi
}
__device__ inline float bf_lo(unsigned int v) { return __uint_as_float(v << 16); }
__device__ inline float bf_hi(unsigned int v) { return __uint_as_float(v & 0xffff0000u); }

// ---------------------------------------------------------------------------
// K1: unified B-operand fragments, 128 cols: n<64 -> l_hat[n], n>=64 -> f2w[n-64].
// Bu4[f*128 + n] = 8 bf16 of src[n][8f..8f+7] (f = 0..63).  (unchanged)
// ---------------------------------------------------------------------------
__global__ void k1_prep(const float* __restrict__ C, const float* __restrict__ f2w,
                        ushort* __restrict__ Bu) {
    const int n = blockIdx.x;            // 0..127
    const float* src = (n < 64) ? (C + n * PP) : (f2w + (n - 64) * PP);
    const int t = threadIdx.x;
    float v0 = src[t];
    float v1 = src[t + 256];
    __shared__ float red[256];
    red[t] = v0 * v0 + v1 * v1;
    __syncthreads();
    for (int s = 128; s > 0; s >>= 1) {
        if (t < s) red[t] += red[t + s];
        __syncthreads();
    }
    const float inv = (n < 64) ? rsqrtf(red[0]) : 1.f;
    Bu[(((t >> 3)       * 128 + n) << 3) + (t & 7)] = (ushort)(pack_bf2(v0 * inv, 0.f) & 0xffffu);
    Bu[((((t + 256) >> 3)) * 128 + n) * 8 + (t & 7)] = (ushort)(pack_bf2(v1 * inv, 0.f) & 0xffffu);
}

// ---------------------------------------------------------------------------
// K2 fused, 512 threads (8 waves) x 2 blocks/CU = 16 waves/CU for latency
// hiding (was 8). Staging: 8 threads/row main, 16 threads/row halo.
// MFMA: 5 tiles -> 5 distinct waves (wall = 1 tile, was 2).
// G (bf16 pairs) + E2 (f32) + sred alias the dead A-tile LDS after MFMA.
// Output: pool[blk][0..63]=partial, [64]=chunk max, [65]=chunk expsum.
// ---------------------------------------------------------------------------
__launch_bounds__(512, 4)   // 4 waves/EU min -> 2 blocks/CU, VGPR cap 128
__global__ void k2_fused(const int* __restrict__ x, const float* __restrict__ V,
                         const uint4* __restrict__ Bu4,
                         const float* __restrict__ f1w, const float* __restrict__ f1b,
                         float* __restrict__ pool) {
    __shared__ uint4 sA[SROWS * 64];     // 75776 B; aliased after MFMA
    __shared__ int   stok[SROWS];
    __shared__ float rnorm[SROWS];
    __shared__ float smv[64];
    __shared__ float sp[64];
    __shared__ float sscal[2];

    const int tid  = threadIdx.x;
    const int lane = tid & 63;
    const int wv   = tid >> 6;           // 0..7
    const int l31  = lane & 31;
    const int b    = blockIdx.x >> 5;
    const int l0   = (blockIdx.x & 31) * 64;

    if (tid < SROWS) {
        int gl = l0 - 5 + tid;
        gl = min(max(gl, 0), LLEN - 1);    // clamp; invalid rows zeroed at G-write
        stok[tid] = x[b * LLEN + tid < SROWS ? gl : 0];
    }
    __syncthreads();

    // ---- staging pass 1: rows 0..63, 8 threads/row, 16 float4 each ----
    {
        const int o = tid & 7;            // octet position within row
        const int r = tid >> 3;           // 0..63
        const float* src = V + (size_t)stok[r] * PP + o * 4;
        const int swzr = r & 7;
        float nrm = 0.f;
        float4 pa[8];
#pragma unroll
        for (int g = 0; g < 8; ++g) pa[g] = ((const float4*)src)[g * 8];
        float4 pb[8];
#pragma unroll
        for (int g = 0; g < 8; ++g) pb[g] = ((const float4*)src)[(g + 8) * 8];
#pragma unroll
        for (int g = 0; g < 8; ++g) {
            const float4 a = pa[g];
            nrm = fmaf(a.x, a.x, fmaf(a.y, a.y, fmaf(a.z, a.z, fmaf(a.w, a.w, nrm))));
            uint2 w2; w2.x = pack_bf2(a.x, a.y); w2.y = pack_bf2(a.z, a.w);
            const int f = g * 4 + (o >> 1);          // float off = o*4+g*32 -> frag f
            ((uint2*)&sA[r * 64 + (f ^ swzr)])[o & 1] = w2;
        }
#pragma unroll
        for (int g = 0; g < 8; ++g) {
            const float4 a = pb[g];
            nrm = fmaf(a.x, a.x, fmaf(a.y, a.y, fmaf(a.z, a.z, fmaf(a.w, a.w, nrm))));
            uint2 w2; w2.x = pack_bf2(a.x, a.y); w2.y = pack_bf2(a.z, a.w);
            const int f = (g + 8) * 4 + (o >> 1);
            ((uint2*)&sA[r * 64 + (f ^ swzr)])[o & 1] = w2;
        }
        nrm += __shfl_xor(nrm, 1, 64);
        nrm += __shfl_xor(nrm, 2, 64);
        nrm += __shfl_xor(nrm, 4, 64);
        if (o == 0) rnorm[r] = rsqrtf(nrm);
    }
    // ---- staging pass 2: halo rows 64..73, 16 threads/row, 8 float4 each ----
    if (tid < 160) {
        const int h16 = tid & 15;
        const int r   = 64 + (tid >> 4);  // 64..73
        const float* src = V + (size_t)stok[r] * PP + h16 * 4;
        const int swzr = r & 7;
        float nrm = 0.f;
        float4 ph[8];
#pragma unroll
        for (int g = 0; g < 8; ++g) ph[g] = ((const float4*)src)[g * 16];
#pragma unroll
        for (int g = 0; g < 8; ++g) {
            const float4 a = ph[g];
            nrm = fmaf(a.x, a.x, fmaf(a.y, a.y, fmaf(a.z, a.z, fmaf(a.w, a.w, nrm))));
            uint2 w2; w2.x = pack_bf2(a.x, a.y); w2.y = pack_bf2(a.z, a.w);
            const int f = g * 8 + (h16 >> 1);        // float off = h16*4+g*64
            ((uint2*)&sA[r * 64 + (f ^ swzr)])[h16 & 1] = w2;
        }
        nrm += __shfl_xor(nrm, 1, 64);
        nrm += __shfl_xor(nrm, 2, 64);
        nrm += __shfl_xor(nrm, 4, 64);
        nrm += __shfl_xor(nrm, 8, 64);
        if (h16 == 0) rnorm[r] = rsqrtf(nrm);
    }
    __syncthreads();

    // ---- MFMA: 5 wave-tiles of 32 rows x 64 cols, one per wave ----
    float16 c0, c1;
#pragma unroll
    for (int i = 0; i < 16; ++i) { c0[i] = 0.f; c1[i] = 0.f; }

    if (wv < 5) {
        const int rowBase = (wv == 0) ? 0 : (wv == 1) ? 32 : (wv == 2) ? 42
                          : (wv == 3) ? 5 : 37;
        const int nh    = (wv < 3) ? 0 : 64;          // cos cols 0-63 / E2 cols 64-127
        const int cc    = lane >> 5;
        const int row   = rowBase + l31;
        const int abase = row * 64;
        const int aswz  = row & 7;
#pragma unroll 8
        for (int ks = 0; ks < 32; ++ks) {
            const int ff = ks * 2 + cc;
            const uint4 av = sA[abase + (ff ^ aswz)];
            const uint4 b0 = Bu4[ff * 128 + nh + l31];
            const uint4 b1 = Bu4[ff * 128 + nh + 32 + l31];
            short8 a8, t0, t1;
            __builtin_memcpy(&a8, &av, 16);
            __builtin_memcpy(&t0, &b0, 16);
            __builtin_memcpy(&t1, &b1, 16);
            c0 = __builtin_amdgcn_mfma_f32_32x32x16_bf16(a8, t0, c0, 0, 0, 0);
            c1 = __builtin_amdgcn_mfma_f32_32x32x16_bf16(a8, t1, c1, 0, 0, 0);
        }
    }
    __syncthreads();   // all A-tile reads done -> safe to alias sA

    // ---- scatter results into aliased LDS ----
    unsigned int* G32 = (unsigned int*)sA;             // [SROWS][32], pairs (j, j+32)
    float*        E2s = (float*)((char*)sA + 10240);   // [64][64] f32 (ends 26624)
    float*        sred = (float*)((char*)sA + 28672);  // [16][64] f32 (ends 32768)
    const int cc = lane >> 5;
    if (wv < 3) {                                       // cos waves
        const int rowBase = (wv == 0) ? 0 : (wv == 1) ? 32 : 42;
#pragma unroll
        for (int reg = 0; reg < 16; ++reg) {
            const int rr  = (reg & 3) + 8 * (reg >> 2) + 4 * cc;
            const int row = rowBase + rr;
            if (wv == 2 && row < 64) continue;          // overlap rows: wv1 owns them
            const int gl = l0 - 5 + row;
            unsigned int vpk = 0u;
            if (gl >= 0 && gl < LLEN) {
                const float rn = rnorm[row];
                vpk = pack_bf2(c0[reg] * rn, c1[reg] * rn);
            }
            G32[row * 32 + l31] = vpk;
        }
    } else if (wv < 5) {                                // E2 waves
        const int rowBase = (wv == 3) ? 5 : 37;
#pragma unroll
        for (int reg = 0; reg < 16; ++reg) {
            const int rr = (reg & 3) + 8 * (reg >> 2) + 4 * cc;
            const int o  = rowBase - 5 + rr;            // 0..63
            E2s[o * 64 + l31]      = c0[reg];
            E2s[o * 64 + 32 + l31] = c1[reg];
        }
    }
    __syncthreads();

    // ---- conv(11) + relu + max over k (512 threads: 16 rows/iter) ----
    float w[11];
#pragma unroll
    for (int t = 0; t < 11; ++t) w[t] = f1w[t];
    const int j = l31;
    const int h = tid >> 5;                              // 0..15
    const float bias0 = f1b[j], bias1 = f1b[j + 32];
#pragma unroll
    for (int i = 0; i < 4; ++i) {
        const int o = i * 16 + h;                        // output row 0..63
        float u0 = 0.f, u1 = 0.f;
#pragma unroll
        for (int tap = 0; tap < 11; ++tap) {
            const unsigned int v = G32[(o + tap) * 32 + j];
            u0 = fmaf(bf_lo(v), w[tap], u0);
            u1 = fmaf(bf_hi(v), w[tap], u1);
        }
        float m = fmaxf(fmaxf(u0 + bias0, 0.f), fmaxf(u1 + bias1, 0.f));
#pragma unroll
        for (int off = 16; off > 0; off >>= 1)
            m = fmaxf(m, __shfl_xor(m, off, 64));        // reduces within 32-lane half
        if (j == 0) smv[o] = m;
    }
    __syncthreads();

    // ---- chunk softmax partials ----
    if (tid < 64) {
        float v = smv[tid];
#pragma unroll
        for (int off = 32; off > 0; off >>= 1)
            v = fmaxf(v, __shfl_xor(v, off, 64));
        if (tid == 0) sscal[0] = v;
    }
    __syncthreads();
    const float mx = sscal[0];
    if (tid < 64) sp[tid] = __expf(smv[tid] - mx);
    __syncthreads();
    if (tid < 64) {
        float s = sp[tid];
#pragma unroll
        for (int off = 32; off > 0; off >>= 1)
            s += __shfl_xor(s, off, 64);
        if (tid == 0) sscal[1] = s;
    }

    // ---- weighted E2 pooling (f32) ----
    float a0 = 0.f, a1 = 0.f;
#pragma unroll
    for (int i = 0; i < 4; ++i) {
        const int o = i * 16 + h;
        const float wgt = sp[o];
        a0 = fmaf(wgt, E2s[o * 64 + j], a0);
        a1 = fmaf(wgt, E2s[o * 64 + 32 + j], a1);
    }
    __syncthreads();          // sp reads done before sred overlaps? (sred disjoint; barrier for E2s reuse-safety not needed, but cheap)
    sred[h * 64 + j]      = a0;
    sred[h * 64 + j + 32] = a1;
    __syncthreads();
    if (tid < 64) {
        float r = 0.f;
#pragma unroll
        for (int hh = 0; hh < 16; ++hh) r += sred[hh * 64 + tid];
        float* dst = pool + (size_t)blockIdx.x * 68;
        dst[tid] = r;
        if (tid == 0) { dst[64] = sscal[0]; dst[65] = sscal[1]; }
    }
}

// ---------------------------------------------------------------------------
// K6: combine 32 chunk-partials per b with online-softmax rescale + head bias.
// ---------------------------------------------------------------------------
__global__ void k6_final(const float* __restrict__ pool, const float* __restrict__ f2b,
                         float* __restrict__ out) {
    const int b = blockIdx.x;
    const int k = threadIdx.x;   // 64 threads
    float M = -1e30f;
#pragma unroll
    for (int c = 0; c < 32; ++c)
        M = fmaxf(M, pool[(size_t)(b * 32 + c) * 68 + 64]);
    float tot = 0.f, num = 0.f;
#pragma unroll
    for (int c = 0; c < 32; ++c) {
        const float* pc = pool + (size_t)(b * 32 + c) * 68;
        const float sc = __expf(pc[64] - M);
        tot = fmaf(sc, pc[65], tot);
        num = fmaf(sc, pc[k], num);
    }
    out[b * KK + k] = (num / tot) * (1.f / 2048.f) + f2b[k];
}

extern "C" void kernel_launch(void* const* d_in, const int* in_sizes, int n_in,
                              void* d_out, int out_size, void* d_ws, size_t ws_size,
                              hipStream_t stream) {
    const int*   x   = (const int*)d_in[0];
    const float* V   = (const float*)d_in[1];
    const float* C   = (const float*)d_in[2];
    const float* f1w = (const float*)d_in[3];
    const float* f1b = (const float*)d_in[4];
    const float* f2w = (const float*)d_in[5];
    const float* f2b = (const float*)d_in[6];
    float* out = (float*)d_out;

    float* ws = (float*)d_ws;
    ushort* Bu = (ushort*)ws;                 // 65536 ushort = 128 KB
    float* pool = ws + 32768;                 // 1024 * 68 floats

    k1_prep <<<128, 256, 0, stream>>>(C, f2w, Bu);
    k2_fused<<<BB * 32, 512, 0, stream>>>(x, V, (const uint4*)Bu, f1w, f1b, pool);
    k6_final<<<BB, 64, 0, stream>>>(pool, f2b, out);
}